// Round 3
// baseline (91.487 us; speedup 1.0000x reference)
//
#include <hip/hip_runtime.h>
#include <stdint.h>

#define D_DIM 128
#define NROW 8192          // 2B
#define L2EPS 1e-12f
// MFMA output = sim * 10/ln2 (exp2 arg): data pre-scaled by sqrt((10/ln2)/16),
// MX scales A=2^4 (131), B=2^0 (127).
#define SCALE_PRE 0.9495707f
#define LN2 0.6931471805599453f
#define NPART 50           // row slots 0..16 (mb), col slots 17..48, diag col 49

typedef __attribute__((ext_vector_type(4))) int   i32x4;
typedef __attribute__((ext_vector_type(8))) int   i32x8;
typedef __attribute__((ext_vector_type(4))) float f32x4;

static __device__ inline i32x8 cat8(i32x4 lo, i32x4 hi) {
    i32x8 r;
    r[0] = lo[0]; r[1] = lo[1]; r[2] = lo[2]; r[3] = lo[3];
    r[4] = hi[0]; r[5] = hi[1]; r[6] = hi[2]; r[7] = hi[3];
    return r;
}

// Native 2^x: our arguments are |x| <= ~15 (sim*10/ln2), far from the
// denormal/overflow edges the OCML exp2f wrapper guards -> raw v_exp_f32.
static __device__ __forceinline__ float fexp2(float x) {
#if __has_builtin(__builtin_amdgcn_exp2f)
    return __builtin_amdgcn_exp2f(x);
#else
    float r;
    asm("v_exp_f32 %0, %1" : "=v"(r) : "v"(x));
    return r;
#endif
}

// Sum over the 16-lane DPP row on the VALU pipe (no ds_bpermute / LDS pipe).
// Result valid in lane 15 of each 16-lane row.
static __device__ __forceinline__ float dpp_row_sum16(float v) {
    union { float f; int i; } u, s;
    u.f = v;
    s.i = __builtin_amdgcn_update_dpp(0, u.i, 0x118, 0xF, 0xF, true); u.f += s.f; // row_shr:8
    s.i = __builtin_amdgcn_update_dpp(0, u.i, 0x114, 0xF, 0xF, true); u.f += s.f; // row_shr:4
    s.i = __builtin_amdgcn_update_dpp(0, u.i, 0x112, 0xF, 0xF, true); u.f += s.f; // row_shr:2
    s.i = __builtin_amdgcn_update_dpp(0, u.i, 0x111, 0xF, 0xF, true); u.f += s.f; // row_shr:1
    return u.f;
}

// K1: L2-normalize rows of [x_i; x_j]; emit ONE fp8 e4m3 array
// z8 = fp8(z * SCALE_PRE), shared by A and B operands (MX scales 2^4 / 2^0
// reconstruct the 10/ln2 factor in the MFMA output).
__global__ __launch_bounds__(256) void k_normalize(
        const float* __restrict__ xi, const float* __restrict__ xj,
        uint8_t* __restrict__ z8, float* __restrict__ pos_acc,
        float* __restrict__ logsum, unsigned* __restrict__ done_ct) {
    const int wave = threadIdx.x >> 6;
    const int lane = threadIdx.x & 63;
    const int row = blockIdx.x * 4 + wave;
    const float* src = (row < 4096) ? (xi + (size_t)row * D_DIM)
                                    : (xj + (size_t)(row - 4096) * D_DIM);
    float2 v = *(const float2*)(src + lane * 2);
    float ss = v.x * v.x + v.y * v.y;
#pragma unroll
    for (int m = 32; m >= 1; m >>= 1) ss += __shfl_xor(ss, m, 64);
    const float scale = SCALE_PRE / fmaxf(sqrtf(ss), L2EPS);
    const int pk = __builtin_amdgcn_cvt_pk_fp8_f32(v.x * scale, v.y * scale, 0, false);
    *(ushort*)(z8 + (size_t)row * D_DIM + lane * 2) = (ushort)pk;

    if (blockIdx.x == 0 && threadIdx.x == 0) {
        pos_acc[0] = 0.0f; logsum[0] = 0.0f; done_ct[0] = 0u;
    }
}

// K2 (paired-circulant symmetric, BARRIER-FREE): block (mb=bid>>6 in 0..16,
// rb=bid&63).
//  mb<16 : rows band rb x col bands c1=(rb+2mb+1)%64, c2=(rb+2mb+2)%64
//          (128x256 tile). Distances 1..31 covered once (full credit);
//          mb==15's second half = distance 32, double-enumerated -> e*=0.5,
//          sub-tile diagonal = positive pairs (both directions accumulated).
//  mb==16: diagonal tile rb x rb, strictly-upper (c>r) only.
// Each e credits denom[row] (slot mb) and denom[col] (slots 17+2mb / +1;
// diag col slot 49). All 50 slots single-writer & fully covered -> no atomics,
// no zeroing.
// NEW vs R0: NO LDS staging of B. z8 is 1 MB -> resident in every XCD's 4 MB
// L2 after first touch; B fragments load straight from global (each j reads a
// contiguous 2 KB region per wave, coalesced). Removes global_load_lds, the
// vmcnt(0) drain, BOTH pre-compute barriers, and all LDS bank conflicts ->
// every wave is an independent load->MFMA->exp stream (grid was phase-locked
// before: all 1088 blocks co-resident staging simultaneously).
// MFMA: mfma_scale_f32_16x16x128_f8f6f4, scale_a=131 (x16), scale_b=127 (x1).
__global__ __launch_bounds__(256, 4) void k_gemm(
        const uint8_t* __restrict__ z8, float* __restrict__ part,
        float* __restrict__ pos_acc) {
    __shared__ float colred[1024];      // col-credit cross-wave reduce only

    const int t = threadIdx.x;
    const int wave = t >> 6, lane = t & 63;
    const int quad = lane >> 4, lc = lane & 15;

    const int mb = blockIdx.x >> 6;     // 0..16
    const int rb = blockIdx.x & 63;
    const int rowbase = rb * 128;
    const bool diag = (mb == 16);
    const int c1 = diag ? rb : (rb + 2 * mb + 1) & 63;
    const int c2 = (rb + 2 * mb + 2) & 63;          // unused when diag

    const uint8_t* zb1 = z8 + (size_t)c1 * 128 * D_DIM;
    const uint8_t* zb2 = z8 + (size_t)c2 * 128 * D_DIM;
    // Per-lane B fragment base within a band: row (j&7)*16+lc, bytes [quad*32,+32)
    const size_t boff = (size_t)lc * D_DIM + quad * 32;
    const uint8_t* bband[2] = { zb1 + boff, (diag ? zb1 : zb2) + boff };

    // A fragments: 32 B of row (rowbase + wave*32 + i*16 + lc), bytes [quad*32,+32).
    i32x8 afr[2];
    {
        const uint8_t* pa = z8 + (size_t)(rowbase + wave * 32 + lc) * D_DIM + quad * 32;
#pragma unroll
        for (int i = 0; i < 2; i++) {
            i32x4 lo = *(const i32x4*)(pa + i * 16 * D_DIM);
            i32x4 hi = *(const i32x4*)(pa + i * 16 * D_DIM + 16);
            afr[i] = cat8(lo, hi);
        }
    }

    float rs[2][4] = {{0.f,0.f,0.f,0.f},{0.f,0.f,0.f,0.f}};
    float cs[16];
#pragma unroll
    for (int j = 0; j < 16; j++) cs[j] = 0.f;
    float posp = 0.f;
    const int rl0 = wave * 32 + quad * 4;   // local row = rl0 + i*16 + r

    // B-row for j: band (j>>3), local row (j&7)*16 + lc, bytes [quad*32,+32).
#define MFMA_J(j, A0, A1)                                                     \
    i32x4 blo, bhi; {                                                         \
        const uint8_t* pb = bband[(j) >> 3] + (size_t)(((j) & 7) * 16) * D_DIM; \
        blo = *(const i32x4*)pb;                                              \
        bhi = *(const i32x4*)(pb + 16);                                       \
    }                                                                         \
    const i32x8 bfr = cat8(blo, bhi);                                         \
    f32x4 z4 = {0.f, 0.f, 0.f, 0.f};                                          \
    f32x4 A0 = __builtin_amdgcn_mfma_scale_f32_16x16x128_f8f6f4(              \
                   afr[0], bfr, z4, 0, 0, 0, 131, 0, 127);                    \
    f32x4 A1 = __builtin_amdgcn_mfma_scale_f32_16x16x128_f8f6f4(              \
                   afr[1], bfr, z4, 0, 0, 0, 131, 0, 127);

    if (!diag) {
#pragma unroll
        for (int j = 0; j < 8; j++) {        // band c1: always full credit
            MFMA_J(j, a0, a1)
#pragma unroll
            for (int r = 0; r < 4; r++) {
                const float e0 = fexp2(a0[r]);
                const float e1 = fexp2(a1[r]);
                rs[0][r] += e0;
                rs[1][r] += e1;
                cs[j] += e0 + e1;
            }
        }
        if (mb < 15) {                        // band c2: full credit
#pragma unroll
            for (int j = 8; j < 16; j++) {
                MFMA_J(j, a0, a1)
#pragma unroll
                for (int r = 0; r < 4; r++) {
                    const float e0 = fexp2(a0[r]);
                    const float e1 = fexp2(a1[r]);
                    rs[0][r] += e0;
                    rs[1][r] += e1;
                    cs[j] += e0 + e1;
                }
            }
        } else {                              // distance-32: halve; diag = positives
#pragma unroll
            for (int j = 8; j < 16; j++) {
                MFMA_J(j, a0, a1)
                const int clb = (j - 8) * 16 + lc;   // band-local col
#pragma unroll
                for (int i = 0; i < 2; i++)
#pragma unroll
                    for (int r = 0; r < 4; r++) {
                        const float s = (i ? a1 : a0)[r];
                        const float e = 0.5f * fexp2(s);
                        if (clb == rl0 + i * 16 + r) posp += s;
                        rs[i][r] += e;
                        cs[j] += e;
                    }
            }
        }
    } else {                                  // diagonal tile: strictly upper
#pragma unroll
        for (int j = 0; j < 8; j++) {
            MFMA_J(j, a0, a1)
            const int cl = j * 16 + lc;
#pragma unroll
            for (int i = 0; i < 2; i++)
#pragma unroll
                for (int r = 0; r < 4; r++) {
                    const float s = (i ? a1 : a0)[r];
                    const float e = (cl > rl0 + i * 16 + r) ? fexp2(s) : 0.f;
                    rs[i][r] += e;
                    cs[j] += e;
                }
        }
    }
#undef MFMA_J

    // Row credits -> slot mb: DPP row-sum over the 16 col-lanes (VALU pipe;
    // result lands in lane 15 of each DPP row).
#pragma unroll
    for (int i = 0; i < 2; i++)
#pragma unroll
        for (int r = 0; r < 4; r++) {
            const float v = dpp_row_sum16(rs[i][r]);
            if (lc == 15)
                part[(size_t)mb * NROW + rowbase + rl0 + i * 16 + r] = v;
        }

    // Col credits: quad-reduce (cross-row -> shfl), cross-wave LDS reduce.
#pragma unroll
    for (int j = 0; j < 16; j++) {
        cs[j] += __shfl_xor(cs[j], 16, 64);
        cs[j] += __shfl_xor(cs[j], 32, 64);
    }
    if (quad == 0) {
#pragma unroll
        for (int j = 0; j < 16; j++)
            colred[wave * 256 + j * 16 + lc] = cs[j];
    }
    __syncthreads();                    // the ONLY barrier in this kernel
    if (t < 256) {
        const float v = colred[t] + colred[256 + t] + colred[512 + t] + colred[768 + t];
        if (!diag) {
            const int slot = 17 + 2 * mb + (t >> 7);
            const int band = (t < 128) ? c1 : c2;
            part[(size_t)slot * NROW + band * 128 + (t & 127)] = v;
        } else if (t < 128) {
            part[(size_t)49 * NROW + c1 * 128 + t] = v;
        }
    }

    if (mb == 15) {
#pragma unroll
        for (int mm = 32; mm >= 1; mm >>= 1) posp += __shfl_xor(posp, mm, 64);
        if (lane == 0) atomicAdd(pos_acc, posp);
    }
}

// K3 (fused logsum + combine): 32 blocks, one row per thread; last block
// (atomic counter) writes the final loss. pos_acc holds scaled sim over both
// appearances of each positive pair -> factor ln2.
__global__ __launch_bounds__(256) void k_logsum(
        const float* __restrict__ part, float* __restrict__ pos_acc,
        float* __restrict__ logsum, unsigned* __restrict__ done_ct,
        float* __restrict__ out) {
    const int row = blockIdx.x * 256 + threadIdx.x;
    float d = 0.f;
#pragma unroll
    for (int p = 0; p < NPART; p++) d += part[(size_t)p * NROW + row];
    float v = __logf(d);
#pragma unroll
    for (int m = 32; m >= 1; m >>= 1) v += __shfl_xor(v, m, 64);
    if ((threadIdx.x & 63) == 0) atomicAdd(logsum, v);
    __threadfence();
    __syncthreads();
    if (threadIdx.x == 0) {
        const unsigned prev = atomicAdd(done_ct, 1u);
        if (prev == gridDim.x - 1) {          // last block: all adds visible
            __threadfence();
            const float ls = atomicAdd(logsum, 0.0f);
            const float pp = atomicAdd(pos_acc, 0.0f);
            out[0] = (ls - pp * LN2) / (float)NROW;
        }
    }
}

extern "C" void kernel_launch(void* const* d_in, const int* in_sizes, int n_in,
                              void* d_out, int out_size, void* d_ws, size_t ws_size,
                              hipStream_t stream) {
    const float* xi = (const float*)d_in[0];
    const float* xj = (const float*)d_in[1];
    uint8_t* z8 = (uint8_t*)d_ws;                                // 1 MB fp8
    float* part = (float*)(z8 + (size_t)NROW * D_DIM);           // 50 x 8192 f32
    float* pos_acc = part + (size_t)NPART * NROW;
    float* logsum = pos_acc + 1;
    unsigned* done_ct = (unsigned*)(logsum + 1);
    float* out = (float*)d_out;

    hipLaunchKernelGGL(k_normalize, dim3(NROW / 4), dim3(256), 0, stream,
                       xi, xj, z8, pos_acc, logsum, done_ct);
    hipLaunchKernelGGL(k_gemm, dim3(17 * 64), dim3(256), 0, stream,
                       z8, part, pos_acc);
    hipLaunchKernelGGL(k_logsum, dim3(NROW / 256), dim3(256), 0, stream,
                       part, pos_acc, logsum, done_ct, out);
}